// Round 8
// baseline (137.234 us; speedup 1.0000x reference)
//
#include <hip/hip_runtime.h>

// RainKAN fused forward via MFMA f16 with REGISTER-RESIDENT W.
//   X[B, K=2048pad] x W[K,64] -> h[B,64] -> exact fp32 KAN layer 2 -> out[B]
// K-steps 0..63 (32 k each; step 63 zero pad). Steps 0..6: silu slots
// (i = st*32+kg*8+j). Steps 7..63: spline slots (i=(st-7)*4+kg, basis j);
// A-frag built in registers from one LDS x read (all 8 bases of one x).
// Block: 512 threads = 8 waves, M=64 samples (4 m-tiles). Wave q = K-eighth:
// steps st ≡ q (mod 8), 8 steps -> B-frags = 8*4 half8 = 128 VGPRs, loaded from
// wcat ONCE and held in registers: the main loop has NO VMEM and NO barriers
// (R3/R4/R6 plateaued at ~40us on per-wave L1-miss B streaming; R7's LDS
// staging serialized on barriers). K-reduction across 8 waves via ds_add_f32.
// W prepped in d_ws fp16 B-frag order: elem(st,nt,lane,j)=W[st*32+(lane>>4)*8+j][nt*16+(lane&15)].

typedef _Float16 half8 __attribute__((ext_vector_type(8)));
typedef float floatx4 __attribute__((ext_vector_type(4)));

#define XR 236   // x-row stride in floats: rows 16B-aligned; 2-way banking (free)

__device__ __forceinline__ float silu_f(float x) {
    return x / (1.0f + __expf(-x));
}

__device__ __forceinline__ void bspline8_dense(float x, float f[8]) {
    float u  = (x + 2.2f) * 2.5f;
    float fj = floorf(u);
    float t  = u - fj;
    int   j  = (int)fj;
    bool valid = (u >= 0.0f) && (u < 11.0f);
    float t2 = t * t, t3 = t2 * t, omt = 1.0f - t;
    float b0 = omt * omt * omt * (1.0f / 6.0f);
    float b1 = (3.0f * t3 - 6.0f * t2 + 4.0f) * (1.0f / 6.0f);
    float b2 = (-3.0f * t3 + 3.0f * t2 + 3.0f * t + 1.0f) * (1.0f / 6.0f);
    float b3 = t3 * (1.0f / 6.0f);
    if (!valid) { b0 = b1 = b2 = b3 = 0.0f; }
    int base = j - 3;
#pragma unroll
    for (int g = 0; g < 8; ++g) {
        int m = g - base;
        float v = (m == 0) ? b0 : 0.0f;
        v = (m == 1) ? b1 : v;
        v = (m == 2) ? b2 : v;
        v = (m == 3) ? b3 : v;
        f[g] = v;
    }
}

// f16 A-fragment: 4 bases placed at half-slots (j-3)..j via 128-bit shift
__device__ __forceinline__ half8 bspline_frag(float x) {
    float u  = (x + 2.2f) * 2.5f;
    float fj = floorf(u);
    float t  = u - fj;
    int   j  = (int)fj;
    bool valid = (u >= 0.0f) && (u < 11.0f);
    float t2 = t * t, t3 = t2 * t, omt = 1.0f - t;
    float b0 = omt * omt * omt * (1.0f / 6.0f);
    float b1 = (3.0f * t3 - 6.0f * t2 + 4.0f) * (1.0f / 6.0f);
    float b2 = (-3.0f * t3 + 3.0f * t2 + 3.0f * t + 1.0f) * (1.0f / 6.0f);
    float b3 = t3 * (1.0f / 6.0f);
    union { _Float16 h[4]; unsigned long long q; } p;
    p.h[0] = (_Float16)b0; p.h[1] = (_Float16)b1;
    p.h[2] = (_Float16)b2; p.h[3] = (_Float16)b3;
    unsigned long long lo = valid ? p.q : 0ull;
    int jc = valid ? j : 3;
    int sh = (jc - 3) * 16;              // bits, in [-48, 112]
    unsigned long long rlo, rhi;
    if (sh >= 0) {
        rlo = (sh < 64) ? (lo << sh) : 0ull;
        rhi = (sh == 0) ? 0ull
            : (sh < 64) ? (lo >> (64 - sh))
                        : (lo << (sh - 64));
    } else {
        rlo = lo >> (-sh);
        rhi = 0ull;
    }
    union { unsigned long long q[2]; half8 v; } r;
    r.q[0] = rlo; r.q[1] = rhi;
    return r.v;
}

// ---- prep: wb1[219,64] + cf1[219,64,8] -> fp16 B-frag wcat[131072] (256 KB) ----
__global__ __launch_bounds__(256) void build_w(
    const float* __restrict__ wb1, const float* __restrict__ cf1,
    _Float16* __restrict__ wcat)
{
    int flat = blockIdx.x * 256 + threadIdx.x;   // < 64*4*64 = 16384
    int lane = flat & 63;
    int nt   = (flat >> 6) & 3;
    int st   = flat >> 8;                        // 0..63
    int kg   = lane >> 4;
    int n    = nt * 16 + (lane & 15);
    _Float16 v[8];
    if (st < 7) {
#pragma unroll
        for (int j = 0; j < 8; ++j) {
            int i = st * 32 + kg * 8 + j;
            v[j] = (_Float16)((i < 219) ? wb1[i * 64 + n] : 0.0f);
        }
    } else {
        int i = (st - 7) * 4 + kg;
#pragma unroll
        for (int j = 0; j < 8; ++j)
            v[j] = (_Float16)((i < 219) ? cf1[(i * 64 + n) * 8 + j] : 0.0f);
    }
    *(half8*)(wcat + (size_t)flat * 8) = *(half8*)v;
}

// ---- fused GEMM + layer 2: 256 blocks x 512 threads, 64 samples/block ----
__global__ __launch_bounds__(512, 2) void kan_mfma(
    const float* __restrict__ hist,    // [B,192]
    const float* __restrict__ statf,   // [B,3]
    const float* __restrict__ timef,   // [B,8]
    const int*   __restrict__ st_idx,  // [B]
    const float* __restrict__ emb,     // [120,16]
    const _Float16* __restrict__ wcat, // [131072]
    const float* __restrict__ wb2,     // [64]
    const float* __restrict__ cf2,     // [64,8]
    float* __restrict__ out)           // [B]
{
    __shared__ union {
        float xb[64 * XR];                                   // 60416 B
        struct { float h[64 * 65]; float part[8 * 64]; } ep; // 18688 B
    } sm;

    const int tid  = threadIdx.x;
    const int lane = tid & 63;
    const int q    = __builtin_amdgcn_readfirstlane(tid >> 6);  // wave = K-eighth
    const int bx   = blockIdx.x;
    const int c15  = lane & 15;
    const int kg   = lane >> 4;

    // ---- stage raw x[64][236] into LDS (slots 219..235 zeroed) ----
    {
        const float4* h4 = (const float4*)hist;   // 48 float4 per row
#pragma unroll
        for (int f = 0; f < 6; ++f) {
            int flat = f * 512 + tid;             // < 3072 = 64*48
            int s  = flat / 48;
            int i4 = flat - s * 48;
            float4 v = h4[(size_t)(bx * 64 + s) * 48 + i4];
            sm.xb[s * XR + i4 * 4 + 0] = v.x;
            sm.xb[s * XR + i4 * 4 + 1] = v.y;
            sm.xb[s * XR + i4 * 4 + 2] = v.z;
            sm.xb[s * XR + i4 * 4 + 3] = v.w;
        }
    }
#pragma unroll
    for (int f = 0; f < 6; ++f) {
        int flat = f * 512 + tid;                 // < 3072 = 64*48
        int s  = flat / 48;
        int ii = 192 + (flat - s * 48);           // 192..239
        int b  = bx * 64 + s;
        float v;
        if (ii < 195)      v = statf[b * 3 + (ii - 192)];
        else if (ii < 203) v = timef[b * 8 + (ii - 195)];
        else if (ii < 219) v = emb[st_idx[b] * 16 + (ii - 203)];
        else               v = 0.0f;
        if (ii < XR) sm.xb[s * XR + ii] = v;
    }
    __syncthreads();

    // ---- load this wave's K-eighth of W into registers (32 KB/wave, once) ----
    half8 breg[8][4];
#pragma unroll
    for (int u = 0; u < 8; ++u) {
        const _Float16* wp = wcat + (size_t)(8 * u + q) * 2048 + lane * 8;
#pragma unroll
        for (int nt = 0; nt < 4; ++nt)
            breg[u][nt] = *(const half8*)(wp + nt * 512);
    }

    floatx4 acc[4][4];
#pragma unroll
    for (int m = 0; m < 4; ++m)
#pragma unroll
        for (int nt = 0; nt < 4; ++nt) acc[m][nt] = (floatx4){0.f, 0.f, 0.f, 0.f};

    // ---- main loop: 8 steps x 4 m-tiles; NO VMEM, NO barriers ----
#pragma unroll
    for (int u = 0; u < 8; ++u) {
        const int st = 8 * u + q;                 // wave-uniform
#pragma unroll
        for (int m = 0; m < 4; ++m) {
            const float* xr = &sm.xb[(m * 16 + c15) * XR];
            half8 af;
            if (u == 0 && st < 7) {               // silu step (waves 0..6, u=0 only)
                const int i0 = st * 32 + kg * 8;
#pragma unroll
                for (int j = 0; j < 8; ++j)
                    af[j] = (_Float16)silu_f(xr[i0 + j]);
            } else {                              // spline step
                af = bspline_frag(xr[(st - 7) * 4 + kg]);
            }
            acc[m][0] = __builtin_amdgcn_mfma_f32_16x16x32_f16(af, breg[u][0], acc[m][0], 0, 0, 0);
            acc[m][1] = __builtin_amdgcn_mfma_f32_16x16x32_f16(af, breg[u][1], acc[m][1], 0, 0, 0);
            acc[m][2] = __builtin_amdgcn_mfma_f32_16x16x32_f16(af, breg[u][2], acc[m][2], 0, 0, 0);
            acc[m][3] = __builtin_amdgcn_mfma_f32_16x16x32_f16(af, breg[u][3], acc[m][3], 0, 0, 0);
        }
    }

    // ---- K-reduction across 8 waves via LDS float atomics ----
    __syncthreads();                              // all xb reads done; reuse LDS
    for (int z = tid; z < 64 * 65; z += 512) sm.ep.h[z] = 0.0f;
    __syncthreads();
    // C/D layout: col = lane&15, row = (lane>>4)*4 + reg
#pragma unroll
    for (int m = 0; m < 4; ++m)
#pragma unroll
        for (int nt = 0; nt < 4; ++nt)
#pragma unroll
            for (int r = 0; r < 4; ++r)
                atomicAdd(&sm.ep.h[(m * 16 + kg * 4 + r) * 65 + nt * 16 + c15],
                          acc[m][nt][r]);
    __syncthreads();

    // ---- exact fp32 layer 2: thread (s = tid&63, og = tid>>6) -> outputs og*8..+8 ----
    {
        const int s  = tid & 63;
        const int og = tid >> 6;                  // 0..7
        float psum = 0.0f;
#pragma unroll
        for (int oo = 0; oo < 8; ++oo) {
            const int o = og * 8 + oo;
            float h = sm.ep.h[s * 65 + o];
            psum = fmaf(silu_f(h), wb2[o], psum);
            float f2[8];
            bspline8_dense(h, f2);
#pragma unroll
            for (int g = 0; g < 8; ++g)
                psum = fmaf(f2[g], cf2[o * 8 + g], psum);
        }
        sm.ep.part[og * 64 + s] = psum;
    }
    __syncthreads();
    if (tid < 64) {
        float r = 0.0f;
#pragma unroll
        for (int og = 0; og < 8; ++og) r += sm.ep.part[og * 64 + tid];
        out[bx * 64 + tid] = r;
    }
}

extern "C" void kernel_launch(void* const* d_in, const int* in_sizes, int n_in,
                              void* d_out, int out_size, void* d_ws, size_t ws_size,
                              hipStream_t stream) {
    const float* hist  = (const float*)d_in[0];
    const float* statf = (const float*)d_in[1];
    const float* timef = (const float*)d_in[2];
    const int*   stidx = (const int*)  d_in[3];
    const float* emb   = (const float*)d_in[4];
    const float* wb1   = (const float*)d_in[5];
    const float* cf1   = (const float*)d_in[6];
    const float* wb2   = (const float*)d_in[7];
    const float* cf2   = (const float*)d_in[8];
    float* out = (float*)d_out;

    _Float16* wcat = (_Float16*)d_ws;   // 131072 fp16 = 256 KB

    build_w<<<64, 256, 0, stream>>>(wb1, cf1, wcat);
    kan_mfma<<<256, 512, 0, stream>>>(hist, statf, timef, stidx, emb,
                                      wcat, wb2, cf2, out);
}

// Round 9
// 124.291 us; speedup vs baseline: 1.1041x; 1.1041x over previous
//
#include <hip/hip_runtime.h>

// RainKAN fused forward via MFMA f16 — W fetched ONCE per CU.
//   X[B, K=2048pad] x W[K,64] -> h[B,64] -> exact fp32 KAN layer 2 -> out[B]
// Model from R2..R8 sweep: wall is per-CU L1 miss-line throughput on the W
// stream (~10 B/cyc/CU; wcat 256 KB >> 32 KB L1 -> 100% miss). Fix: M=64/block,
// 256 blocks = 1 block/CU; 4 waves = 4 K-quarters, each step's 4 KB loaded by
// exactly ONE wave; wave computes all 4 m-tiles -> per-CU W traffic 256 KB
// (4x less than R6's 1 MB). B streams through VGPRs (NOT register-resident:
// R8 spilled at breg=128). K-steps 0..63: st<7 silu slots (i=st*32+kg*8+j),
// st>=7 spline slots (i=(st-7)*4+kg, basis j); A-frag built in registers from
// one LDS x-read (all 8 bases of one x, placed via 128-bit funnel shift).
// W prepped in d_ws fp16 B-frag order: elem(st,nt,lane,j)=W[st*32+(lane>>4)*8+j][nt*16+(lane&15)].

typedef _Float16 half8 __attribute__((ext_vector_type(8)));
typedef float floatx4 __attribute__((ext_vector_type(4)));

#define XR 236   // x-row stride in floats: 16B-aligned rows; 2-way banking (free)

__device__ __forceinline__ float silu_f(float x) {
    return x / (1.0f + __expf(-x));
}

__device__ __forceinline__ void bspline8_dense(float x, float f[8]) {
    float u  = (x + 2.2f) * 2.5f;
    float fj = floorf(u);
    float t  = u - fj;
    int   j  = (int)fj;
    bool valid = (u >= 0.0f) && (u < 11.0f);
    float t2 = t * t, t3 = t2 * t, omt = 1.0f - t;
    float b0 = omt * omt * omt * (1.0f / 6.0f);
    float b1 = (3.0f * t3 - 6.0f * t2 + 4.0f) * (1.0f / 6.0f);
    float b2 = (-3.0f * t3 + 3.0f * t2 + 3.0f * t + 1.0f) * (1.0f / 6.0f);
    float b3 = t3 * (1.0f / 6.0f);
    if (!valid) { b0 = b1 = b2 = b3 = 0.0f; }
    int base = j - 3;
#pragma unroll
    for (int g = 0; g < 8; ++g) {
        int m = g - base;
        float v = (m == 0) ? b0 : 0.0f;
        v = (m == 1) ? b1 : v;
        v = (m == 2) ? b2 : v;
        v = (m == 3) ? b3 : v;
        f[g] = v;
    }
}

// f16 A-fragment: 4 bases placed at half-slots (j-3)..j via 128-bit shift
__device__ __forceinline__ half8 bspline_frag(float x) {
    float u  = (x + 2.2f) * 2.5f;
    float fj = floorf(u);
    float t  = u - fj;
    int   j  = (int)fj;
    bool valid = (u >= 0.0f) && (u < 11.0f);
    float t2 = t * t, t3 = t2 * t, omt = 1.0f - t;
    float b0 = omt * omt * omt * (1.0f / 6.0f);
    float b1 = (3.0f * t3 - 6.0f * t2 + 4.0f) * (1.0f / 6.0f);
    float b2 = (-3.0f * t3 + 3.0f * t2 + 3.0f * t + 1.0f) * (1.0f / 6.0f);
    float b3 = t3 * (1.0f / 6.0f);
    union { _Float16 h[4]; unsigned long long q; } p;
    p.h[0] = (_Float16)b0; p.h[1] = (_Float16)b1;
    p.h[2] = (_Float16)b2; p.h[3] = (_Float16)b3;
    unsigned long long lo = valid ? p.q : 0ull;
    int jc = valid ? j : 3;
    int sh = (jc - 3) * 16;              // bits, in [-48, 112]
    unsigned long long rlo, rhi;
    if (sh >= 0) {
        rlo = (sh < 64) ? (lo << sh) : 0ull;
        rhi = (sh == 0) ? 0ull
            : (sh < 64) ? (lo >> (64 - sh))
                        : (lo << (sh - 64));
    } else {
        rlo = lo >> (-sh);
        rhi = 0ull;
    }
    union { unsigned long long q[2]; half8 v; } r;
    r.q[0] = rlo; r.q[1] = rhi;
    return r.v;
}

// ---- prep: wb1[219,64] + cf1[219,64,8] -> fp16 B-frag wcat[131072] (256 KB) ----
__global__ __launch_bounds__(256) void build_w(
    const float* __restrict__ wb1, const float* __restrict__ cf1,
    _Float16* __restrict__ wcat)
{
    int flat = blockIdx.x * 256 + threadIdx.x;   // < 64*4*64 = 16384
    int lane = flat & 63;
    int nt   = (flat >> 6) & 3;
    int st   = flat >> 8;                        // 0..63
    int kg   = lane >> 4;
    int n    = nt * 16 + (lane & 15);
    _Float16 v[8];
    if (st < 7) {
#pragma unroll
        for (int j = 0; j < 8; ++j) {
            int i = st * 32 + kg * 8 + j;
            v[j] = (_Float16)((i < 219) ? wb1[i * 64 + n] : 0.0f);
        }
    } else {
        int i = (st - 7) * 4 + kg;
#pragma unroll
        for (int j = 0; j < 8; ++j)
            v[j] = (_Float16)((i < 219) ? cf1[(i * 64 + n) * 8 + j] : 0.0f);
    }
    *(half8*)(wcat + (size_t)flat * 8) = *(half8*)v;
}

// ---- fused GEMM + layer 2: 256 blocks x 256 threads, 64 samples/block ----
__global__ __launch_bounds__(256) void kan_mfma(
    const float* __restrict__ hist,    // [B,192]
    const float* __restrict__ statf,   // [B,3]
    const float* __restrict__ timef,   // [B,8]
    const int*   __restrict__ st_idx,  // [B]
    const float* __restrict__ emb,     // [120,16]
    const _Float16* __restrict__ wcat, // [131072]
    const float* __restrict__ wb2,     // [64]
    const float* __restrict__ cf2,     // [64,8]
    float* __restrict__ out)           // [B]
{
    __shared__ union {
        float xb[64 * XR];                                   // 60416 B
        struct { float h[64 * 65]; float part[4 * 64]; } ep; // 17664 B
    } sm;

    const int tid  = threadIdx.x;
    const int lane = tid & 63;
    const int q    = __builtin_amdgcn_readfirstlane(tid >> 6);  // wave = K-quarter
    const int bx   = blockIdx.x;
    const int c15  = lane & 15;
    const int kg   = lane >> 4;

    // ---- stage raw x[64][236] into LDS (slots 219..235 zeroed) ----
    {
        const float4* h4 = (const float4*)hist;   // 48 float4 per row
#pragma unroll
        for (int f = 0; f < 12; ++f) {
            int flat = f * 256 + tid;             // < 3072 = 64*48
            int s  = flat / 48;
            int i4 = flat - s * 48;
            float4 v = h4[(size_t)(bx * 64 + s) * 48 + i4];
            sm.xb[s * XR + i4 * 4 + 0] = v.x;
            sm.xb[s * XR + i4 * 4 + 1] = v.y;
            sm.xb[s * XR + i4 * 4 + 2] = v.z;
            sm.xb[s * XR + i4 * 4 + 3] = v.w;
        }
    }
#pragma unroll
    for (int f = 0; f < 12; ++f) {
        int flat = f * 256 + tid;                 // < 3072 = 64*48
        int s  = flat / 48;
        int ii = 192 + (flat - s * 48);           // 192..239
        int b  = bx * 64 + s;
        float v;
        if (ii < 195)      v = statf[b * 3 + (ii - 192)];
        else if (ii < 203) v = timef[b * 8 + (ii - 195)];
        else if (ii < 219) v = emb[st_idx[b] * 16 + (ii - 203)];
        else               v = 0.0f;
        if (ii < XR) sm.xb[s * XR + ii] = v;
    }
    __syncthreads();

    floatx4 acc[4][4];
#pragma unroll
    for (int m = 0; m < 4; ++m)
#pragma unroll
        for (int nt = 0; nt < 4; ++nt) acc[m][nt] = (floatx4){0.f, 0.f, 0.f, 0.f};

    // ---- silu steps: st = q, q+4, ... < 7 (each step's W loaded by ONE wave) ----
    for (int st = q; st < 7; st += 4) {
        const _Float16* wp = wcat + (size_t)(st * 4) * 512 + lane * 8;
        half8 bf0 = *(const half8*)(wp);
        half8 bf1 = *(const half8*)(wp + 512);
        half8 bf2 = *(const half8*)(wp + 1024);
        half8 bf3 = *(const half8*)(wp + 1536);
        const int i0 = st * 32 + kg * 8;
#pragma unroll
        for (int m = 0; m < 4; ++m) {
            const float* xr = &sm.xb[(m * 16 + c15) * XR];
            half8 af;
#pragma unroll
            for (int j = 0; j < 8; ++j)
                af[j] = (_Float16)silu_f(xr[i0 + j]);
            acc[m][0] = __builtin_amdgcn_mfma_f32_16x16x32_f16(af, bf0, acc[m][0], 0, 0, 0);
            acc[m][1] = __builtin_amdgcn_mfma_f32_16x16x32_f16(af, bf1, acc[m][1], 0, 0, 0);
            acc[m][2] = __builtin_amdgcn_mfma_f32_16x16x32_f16(af, bf2, acc[m][2], 0, 0, 0);
            acc[m][3] = __builtin_amdgcn_mfma_f32_16x16x32_f16(af, bf3, acc[m][3], 0, 0, 0);
        }
    }

    // ---- spline steps: st >= 7, st ≡ q (mod 4), through padded step 63 ----
    {
        int st = 7 + ((q - 3) & 3);               // first st>=7 with st%4==q
#pragma unroll 2
        for (; st < 64; st += 4) {
            const _Float16* wp = wcat + (size_t)(st * 4) * 512 + lane * 8;
            half8 bf0 = *(const half8*)(wp);
            half8 bf1 = *(const half8*)(wp + 512);
            half8 bf2 = *(const half8*)(wp + 1024);
            half8 bf3 = *(const half8*)(wp + 1536);
            const int xo = (st - 7) * 4 + kg;
#pragma unroll
            for (int m = 0; m < 4; ++m) {
                half8 af = bspline_frag(sm.xb[(m * 16 + c15) * XR + xo]);
                acc[m][0] = __builtin_amdgcn_mfma_f32_16x16x32_f16(af, bf0, acc[m][0], 0, 0, 0);
                acc[m][1] = __builtin_amdgcn_mfma_f32_16x16x32_f16(af, bf1, acc[m][1], 0, 0, 0);
                acc[m][2] = __builtin_amdgcn_mfma_f32_16x16x32_f16(af, bf2, acc[m][2], 0, 0, 0);
                acc[m][3] = __builtin_amdgcn_mfma_f32_16x16x32_f16(af, bf3, acc[m][3], 0, 0, 0);
            }
        }
    }

    // ---- K-reduction across 4 waves via LDS float atomics ----
    __syncthreads();                              // all xb reads done; reuse LDS
    for (int z = tid; z < 64 * 65; z += 256) sm.ep.h[z] = 0.0f;
    __syncthreads();
    // C/D layout: col = lane&15, row = (lane>>4)*4 + reg
#pragma unroll
    for (int m = 0; m < 4; ++m)
#pragma unroll
        for (int nt = 0; nt < 4; ++nt)
#pragma unroll
            for (int r = 0; r < 4; ++r)
                atomicAdd(&sm.ep.h[(m * 16 + kg * 4 + r) * 65 + nt * 16 + c15],
                          acc[m][nt][r]);
    __syncthreads();

    // ---- exact fp32 layer 2: thread (s = tid&63, og = tid>>6) -> outputs og*16..+16 ----
    {
        const int s  = tid & 63;
        const int og = tid >> 6;                  // 0..3
        float psum = 0.0f;
#pragma unroll
        for (int oo = 0; oo < 16; ++oo) {
            const int o = og * 16 + oo;
            float h = sm.ep.h[s * 65 + o];
            psum = fmaf(silu_f(h), wb2[o], psum);
            float f2[8];
            bspline8_dense(h, f2);
#pragma unroll
            for (int g = 0; g < 8; ++g)
                psum = fmaf(f2[g], cf2[o * 8 + g], psum);
        }
        sm.ep.part[og * 64 + s] = psum;
    }
    __syncthreads();
    if (tid < 64)
        out[bx * 64 + tid] = sm.ep.part[tid] + sm.ep.part[64 + tid] +
                             sm.ep.part[128 + tid] + sm.ep.part[192 + tid];
}

extern "C" void kernel_launch(void* const* d_in, const int* in_sizes, int n_in,
                              void* d_out, int out_size, void* d_ws, size_t ws_size,
                              hipStream_t stream) {
    const float* hist  = (const float*)d_in[0];
    const float* statf = (const float*)d_in[1];
    const float* timef = (const float*)d_in[2];
    const int*   stidx = (const int*)  d_in[3];
    const float* emb   = (const float*)d_in[4];
    const float* wb1   = (const float*)d_in[5];
    const float* cf1   = (const float*)d_in[6];
    const float* wb2   = (const float*)d_in[7];
    const float* cf2   = (const float*)d_in[8];
    float* out = (float*)d_out;

    _Float16* wcat = (_Float16*)d_ws;   // 131072 fp16 = 256 KB

    build_w<<<64, 256, 0, stream>>>(wb1, cf1, wcat);
    kan_mfma<<<256, 256, 0, stream>>>(hist, statf, timef, stidx, emb,
                                      wcat, wb2, cf2, out);
}

// Round 11
// 114.796 us; speedup vs baseline: 1.1955x; 1.0827x over previous
//
#include <hip/hip_runtime.h>

// RainKAN fused forward, v11: K split across blocks; W-slice LDS-resident;
// inner loop: ZERO VMEM-for-W, ZERO barriers. Fixes R10's bug (two K-half
// waves overwrote the same partials): wave = m-tile, runs ALL 8 steps of the
// block's K-slice, so every (ks,sample,o) partial has exactly one writer.
//   K1: X[16384, K=2048pad] x W[K,64] -> fp32 partials p[8][16384][64] in d_ws
//   K2: reduce over 8 K-slices + exact fp32 KAN layer 2 -> out[16384]
// K-steps 0..63 (32 k each; step 63 zero-pad). st<7: silu slots (i=st*32+kg*8+j).
// st>=7: spline slots (i=(st-7)*4+kg, basis j); A-frag = all 8 bases of one x,
// built in registers (128-bit funnel-shift placement).
// K1 grid: blk = bx*8+ks; bx sample-block (M=64), ks K-slice (8 steps, 32 KB W).
// x is gathered per-lane from global; each wave touches only its 16 sample rows
// (~12 KB) across all steps -> L1-resident after first touch.
// W prepped fp16 B-frag order: elem(st,nt,lane,j)=W[st*32+(lane>>4)*8+j][nt*16+(lane&15)].

typedef _Float16 half8 __attribute__((ext_vector_type(8)));
typedef float floatx4 __attribute__((ext_vector_type(4)));

__device__ __forceinline__ float silu_f(float x) {
    return x / (1.0f + __expf(-x));
}

__device__ __forceinline__ float load_x(
    const float* __restrict__ hist, const float* __restrict__ statf,
    const float* __restrict__ timef, const int* __restrict__ st_idx,
    const float* __restrict__ emb, int b, int i)
{
    if (i < 192) return hist[(size_t)b * 192 + i];
    if (i < 195) return statf[b * 3 + (i - 192)];
    if (i < 203) return timef[b * 8 + (i - 195)];
    if (i < 219) return emb[st_idx[b] * 16 + (i - 203)];
    return 0.0f;
}

__device__ __forceinline__ void bspline8_dense(float x, float f[8]) {
    float u  = (x + 2.2f) * 2.5f;
    float fj = floorf(u);
    float t  = u - fj;
    int   j  = (int)fj;
    bool valid = (u >= 0.0f) && (u < 11.0f);
    float t2 = t * t, t3 = t2 * t, omt = 1.0f - t;
    float b0 = omt * omt * omt * (1.0f / 6.0f);
    float b1 = (3.0f * t3 - 6.0f * t2 + 4.0f) * (1.0f / 6.0f);
    float b2 = (-3.0f * t3 + 3.0f * t2 + 3.0f * t + 1.0f) * (1.0f / 6.0f);
    float b3 = t3 * (1.0f / 6.0f);
    if (!valid) { b0 = b1 = b2 = b3 = 0.0f; }
    int base = j - 3;
#pragma unroll
    for (int g = 0; g < 8; ++g) {
        int m = g - base;
        float v = (m == 0) ? b0 : 0.0f;
        v = (m == 1) ? b1 : v;
        v = (m == 2) ? b2 : v;
        v = (m == 3) ? b3 : v;
        f[g] = v;
    }
}

// f16 A-fragment: 4 bases placed at half-slots (j-3)..j via 128-bit shift
__device__ __forceinline__ half8 bspline_frag(float x) {
    float u  = (x + 2.2f) * 2.5f;
    float fj = floorf(u);
    float t  = u - fj;
    int   j  = (int)fj;
    bool valid = (u >= 0.0f) && (u < 11.0f);
    float t2 = t * t, t3 = t2 * t, omt = 1.0f - t;
    float b0 = omt * omt * omt * (1.0f / 6.0f);
    float b1 = (3.0f * t3 - 6.0f * t2 + 4.0f) * (1.0f / 6.0f);
    float b2 = (-3.0f * t3 + 3.0f * t2 + 3.0f * t + 1.0f) * (1.0f / 6.0f);
    float b3 = t3 * (1.0f / 6.0f);
    union { _Float16 h[4]; unsigned long long q; } p;
    p.h[0] = (_Float16)b0; p.h[1] = (_Float16)b1;
    p.h[2] = (_Float16)b2; p.h[3] = (_Float16)b3;
    unsigned long long lo = valid ? p.q : 0ull;
    int jc = valid ? j : 3;
    int sh = (jc - 3) * 16;              // bits, in [-48, 112]
    unsigned long long rlo, rhi;
    if (sh >= 0) {
        rlo = (sh < 64) ? (lo << sh) : 0ull;
        rhi = (sh == 0) ? 0ull
            : (sh < 64) ? (lo >> (64 - sh))
                        : (lo << (sh - 64));
    } else {
        rlo = lo >> (-sh);
        rhi = 0ull;
    }
    union { unsigned long long q[2]; half8 v; } r;
    r.q[0] = rlo; r.q[1] = rhi;
    return r.v;
}

// ---- prep: wb1[219,64] + cf1[219,64,8] -> fp16 B-frag wcat[131072] (256 KB) ----
__global__ __launch_bounds__(256) void build_w(
    const float* __restrict__ wb1, const float* __restrict__ cf1,
    _Float16* __restrict__ wcat)
{
    int flat = blockIdx.x * 256 + threadIdx.x;   // < 64*4*64 = 16384
    int lane = flat & 63;
    int nt   = (flat >> 6) & 3;
    int st   = flat >> 8;                        // 0..63
    int kg   = lane >> 4;
    int n    = nt * 16 + (lane & 15);
    _Float16 v[8];
    if (st < 7) {
#pragma unroll
        for (int j = 0; j < 8; ++j) {
            int i = st * 32 + kg * 8 + j;
            v[j] = (_Float16)((i < 219) ? wb1[i * 64 + n] : 0.0f);
        }
    } else {
        int i = (st - 7) * 4 + kg;
#pragma unroll
        for (int j = 0; j < 8; ++j)
            v[j] = (_Float16)((i < 219) ? cf1[(i * 64 + n) * 8 + j] : 0.0f);
    }
    *(half8*)(wcat + (size_t)flat * 8) = *(half8*)v;
}

// ---- K1: 2048 blocks x 256 threads; blk = bx*8 + ks; wave = m-tile ----
__global__ __launch_bounds__(256) void kan_mfma(
    const float* __restrict__ hist,    // [B,192]
    const float* __restrict__ statf,   // [B,3]
    const float* __restrict__ timef,   // [B,8]
    const int*   __restrict__ st_idx,  // [B]
    const float* __restrict__ emb,     // [120,16]
    const _Float16* __restrict__ wcat, // [131072]
    float* __restrict__ pbuf)          // [8][16384][64] partials
{
    __shared__ _Float16 wslice[8 * 2048];        // 32 KB: this block's K-slice

    const int tid  = threadIdx.x;
    const int lane = tid & 63;
    const int mt   = __builtin_amdgcn_readfirstlane(tid >> 6);  // m-tile 0..3
    const int blk  = blockIdx.x;
    const int ks   = blk & 7;          // K-slice (8 steps)
    const int bx   = blk >> 3;         // sample-block (M=64), 0..255
    const int c15  = lane & 15;
    const int kg   = lane >> 4;

    // ---- one-shot W-slice stage: 32 KB, register-batched, coalesced ----
    {
        half8 tmp[8];
        const _Float16* src = wcat + (size_t)ks * 16384;
#pragma unroll
        for (int f = 0; f < 8; ++f)
            tmp[f] = *(const half8*)(src + (size_t)(f * 256 + tid) * 8);
#pragma unroll
        for (int f = 0; f < 8; ++f)
            *(half8*)&wslice[(f * 256 + tid) * 8] = tmp[f];
    }
    __syncthreads();                   // the ONLY barrier

    const int brow = bx * 64 + mt * 16 + c15;    // this lane's sample row

    floatx4 acc[4];
#pragma unroll
    for (int nt = 0; nt < 4; ++nt) acc[nt] = (floatx4){0.f, 0.f, 0.f, 0.f};

    // ---- 8 steps: pure LDS + registers, no barriers, no K-overlap ----
#pragma unroll
    for (int u = 0; u < 8; ++u) {
        const int st = ks * 8 + u;               // global K-step (block-uniform)
        const _Float16* bp = &wslice[u * 2048 + lane * 8];
        half8 bf0 = *(const half8*)(bp);
        half8 bf1 = *(const half8*)(bp + 512);
        half8 bf2 = *(const half8*)(bp + 1024);
        half8 bf3 = *(const half8*)(bp + 1536);

        half8 af;
        if (st < 6) {                            // silu, pure-hist fast path
            const float4* hp = (const float4*)(hist + (size_t)brow * 192 + st * 32 + kg * 8);
            float4 xa = hp[0], xc = hp[1];
            af[0] = (_Float16)silu_f(xa.x); af[1] = (_Float16)silu_f(xa.y);
            af[2] = (_Float16)silu_f(xa.z); af[3] = (_Float16)silu_f(xa.w);
            af[4] = (_Float16)silu_f(xc.x); af[5] = (_Float16)silu_f(xc.y);
            af[6] = (_Float16)silu_f(xc.z); af[7] = (_Float16)silu_f(xc.w);
        } else if (st == 6) {                    // silu, piecewise tail
#pragma unroll
            for (int j = 0; j < 8; ++j)
                af[j] = (_Float16)silu_f(load_x(hist, statf, timef, st_idx, emb,
                                                brow, 192 + kg * 8 + j));
        } else {                                 // spline step
            float x = load_x(hist, statf, timef, st_idx, emb,
                             brow, (st - 7) * 4 + kg);
            af = bspline_frag(x);
        }
        acc[0] = __builtin_amdgcn_mfma_f32_16x16x32_f16(af, bf0, acc[0], 0, 0, 0);
        acc[1] = __builtin_amdgcn_mfma_f32_16x16x32_f16(af, bf1, acc[1], 0, 0, 0);
        acc[2] = __builtin_amdgcn_mfma_f32_16x16x32_f16(af, bf2, acc[2], 0, 0, 0);
        acc[3] = __builtin_amdgcn_mfma_f32_16x16x32_f16(af, bf3, acc[3], 0, 0, 0);
    }

    // ---- store partials: p[ks][sample][o]; C/D: col=c15 -> o-part, row=kg*4+r ----
    // sample = bx*64 + mt*16 + kg*4 + r ; o = nt*16 + c15 ; unique writer per elem.
    float* pp = pbuf + ((size_t)ks * 16384 + (size_t)bx * 64 + mt * 16 + kg * 4) * 64 + c15;
#pragma unroll
    for (int nt = 0; nt < 4; ++nt)
#pragma unroll
        for (int r = 0; r < 4; ++r)
            pp[(size_t)r * 64 + nt * 16] = acc[nt][r];
}

// ---- K2: reduce over 8 K-slices + exact fp32 layer 2: 512 blocks x 256 thr ----
__global__ __launch_bounds__(256) void kan_l2(
    const float* __restrict__ pbuf,    // [8][16384][64]
    const float* __restrict__ wb2,     // [64]
    const float* __restrict__ cf2,     // [64,8]
    float* __restrict__ out)           // [16384]
{
    __shared__ float h[32 * 65];
    __shared__ float part[8 * 32];

    const int tid = threadIdx.x;
    const int bx  = blockIdx.x;        // 32 samples: s0 = bx*32

    float racc[8];
#pragma unroll
    for (int z = 0; z < 8; ++z) racc[z] = 0.0f;
#pragma unroll
    for (int ks = 0; ks < 8; ++ks) {
        const float* pk = pbuf + (size_t)ks * 1048576 + (size_t)bx * 2048;
#pragma unroll
        for (int z = 0; z < 8; ++z)
            racc[z] += pk[z * 256 + tid];        // coalesced
    }
#pragma unroll
    for (int z = 0; z < 8; ++z) {
        int f = z * 256 + tid;                   // f = s*64 + o
        h[(f >> 6) * 65 + (f & 63)] = racc[z];
    }
    __syncthreads();

    {
        const int s  = tid & 31;
        const int og = tid >> 5;                 // 0..7, outputs og*8..+8
        float psum = 0.0f;
#pragma unroll
        for (int oo = 0; oo < 8; ++oo) {
            const int o = og * 8 + oo;
            float hv = h[s * 65 + o];
            psum = fmaf(silu_f(hv), wb2[o], psum);
            float f2[8];
            bspline8_dense(hv, f2);
#pragma unroll
            for (int g = 0; g < 8; ++g)
                psum = fmaf(f2[g], cf2[o * 8 + g], psum);
        }
        part[og * 32 + s] = psum;
    }
    __syncthreads();
    if (tid < 32) {
        float r = 0.0f;
#pragma unroll
        for (int og = 0; og < 8; ++og) r += part[og * 32 + tid];
        out[bx * 32 + tid] = r;
    }
}

extern "C" void kernel_launch(void* const* d_in, const int* in_sizes, int n_in,
                              void* d_out, int out_size, void* d_ws, size_t ws_size,
                              hipStream_t stream) {
    const float* hist  = (const float*)d_in[0];
    const float* statf = (const float*)d_in[1];
    const float* timef = (const float*)d_in[2];
    const int*   stidx = (const int*)  d_in[3];
    const float* emb   = (const float*)d_in[4];
    const float* wb1   = (const float*)d_in[5];
    const float* cf1   = (const float*)d_in[6];
    const float* wb2   = (const float*)d_in[7];
    const float* cf2   = (const float*)d_in[8];
    float* out = (float*)d_out;

    _Float16* wcat = (_Float16*)d_ws;                       // 256 KB at offset 0
    float*    pbuf = (float*)((char*)d_ws + (1 << 20));     // 32 MB partials at +1 MB

    build_w<<<64, 256, 0, stream>>>(wb1, cf1, wcat);
    kan_mfma<<<2048, 256, 0, stream>>>(hist, statf, timef, stidx, emb, wcat, pbuf);
    kan_l2<<<512, 256, 0, stream>>>(pbuf, wb2, cf2, out);
}